// Round 6
// baseline (431.890 us; speedup 1.0000x reference)
//
#include <hip/hip_runtime.h>
#include <stddef.h>
#include <stdint.h>

// ---------- problem dims (fixed by setup_inputs) ----------
#define BDIM 2
#define SDIM 2048
#define DDIM 1024
#define FDIM 4096
#define ENUM 8
#define KSEL 2
#define TTOK (BDIM * SDIM)        // 4096 tokens
#define PPAIR (TTOK * KSEL)       // 8192 (token,k) pairs
#define VOUT ((size_t)TTOK * DDIM) // 4194304 floats of "mixed"
#define MB2MAX 40                 // 256-granular m-blocks: sum ceil(cnt_e/256) <= 32+8

typedef float f32x4 __attribute__((ext_vector_type(4)));
typedef short bf16x8 __attribute__((ext_vector_type(8)));
typedef unsigned short u16x8 __attribute__((ext_vector_type(8)));
typedef unsigned short u16x4 __attribute__((ext_vector_type(4)));

#define WAITV(N) asm volatile("s_waitcnt vmcnt(" #N ")" ::: "memory")
#define BAR() __builtin_amdgcn_s_barrier()

__device__ __forceinline__ unsigned short f2bf(float f) {
  unsigned int u = __float_as_uint(f);
  u += 0x7fffu + ((u >> 16) & 1u);   // RNE
  return (unsigned short)(u >> 16);
}

__device__ __forceinline__ float gelu_tanh(float x) {
  float u = 0.7978845608028654f * (x + 0.044715f * x * x * x);
  float e = __expf(2.0f * u);
  float t = 1.0f - 2.0f / (e + 1.0f);   // tanh(u), safe at +-inf
  return 0.5f * x * (1.0f + t);
}

__device__ __forceinline__ void gload16(const void* g, void* l) {
  __builtin_amdgcn_global_load_lds(
      (const __attribute__((address_space(1))) unsigned int*)g,
      (__attribute__((address_space(3))) unsigned int*)l, 16, 0, 0);
}

// ---------- router stats, stage A ----------
__global__ __launch_bounds__(256) void statsA_kernel(const float* __restrict__ lg,
                                                     float* __restrict__ pst) {
  __shared__ float se[256], sm[256];
  const int r = blockIdx.x * 256 + threadIdx.x;
  float v[ENUM];
  float mx = -1e30f;
#pragma unroll
  for (int i = 0; i < ENUM; ++i) { v[i] = lg[r * ENUM + i]; mx = fmaxf(mx, v[i]); }
  float s = 0.f;
#pragma unroll
  for (int i = 0; i < ENUM; ++i) { v[i] = __expf(v[i] - mx); s += v[i]; }
  float inv = 1.f / s;
  float p1 = -1.f, p2 = -1.f, e_ = 0.f;
#pragma unroll
  for (int i = 0; i < ENUM; ++i) {
    float p = v[i] * inv;
    e_ -= p * logf(fmaxf(p, 1e-9f));
    if (p > p1) { p2 = p1; p1 = p; } else if (p > p2) { p2 = p; }
  }
  se[threadIdx.x] = e_; sm[threadIdx.x] = p1 - p2;
  __syncthreads();
  for (int st = 128; st > 0; st >>= 1) {
    if (threadIdx.x < (unsigned)st) { se[threadIdx.x] += se[threadIdx.x + st]; sm[threadIdx.x] += sm[threadIdx.x + st]; }
    __syncthreads();
  }
  if (threadIdx.x == 0) { pst[blockIdx.x * 2] = se[0]; pst[blockIdx.x * 2 + 1] = sm[0]; }
}

// ---------- router stats, stage B ----------
__global__ void statsB_kernel(const float* __restrict__ pst, float* __restrict__ out) {
  if (threadIdx.x == 0) {
    float a = 0.f, b = 0.f;
    for (int i = 0; i < 16; ++i) { a += pst[2 * i]; b += pst[2 * i + 1]; }
    out[VOUT]     = a / (float)TTOK;
    out[VOUT + 1] = b / (float)TTOK;
  }
}

// ---------- routing: group pairs by expert; 256-granular block table ----------
__global__ __launch_bounds__(256) void routing_kernel(const int* __restrict__ eidx,
                                                      int* __restrict__ g_cnt,
                                                      int* __restrict__ g_off,
                                                      int* __restrict__ pairTok,
                                                      int* __restrict__ inv,
                                                      int* __restrict__ blkE2,
                                                      int* __restrict__ blkM2,
                                                      int* __restrict__ nMB2) {
  __shared__ int sc[ENUM], so[ENUM], scur[ENUM];
  const int tid = threadIdx.x;
  if (tid < ENUM) sc[tid] = 0;
  __syncthreads();
  for (int p = tid; p < PPAIR; p += 256) atomicAdd(&sc[eidx[p]], 1);
  __syncthreads();
  if (tid == 0) {
    int o = 0, nb2 = 0;
    for (int e = 0; e < ENUM; ++e) {
      so[e] = o;
      for (int m0 = 0; m0 < sc[e]; m0 += 256) { blkE2[nb2] = e; blkM2[nb2] = m0; ++nb2; }
      o += sc[e];
    }
    nMB2[0] = nb2;
  }
  __syncthreads();
  if (tid < ENUM) { scur[tid] = so[tid]; g_cnt[tid] = sc[tid]; g_off[tid] = so[tid]; }
  __syncthreads();
  for (int p = tid; p < PPAIR; p += 256) {
    int e = eidx[p];
    int pos = atomicAdd(&scur[e], 1);
    pairTok[pos] = p >> 1;  // token id
    inv[p] = pos;           // grouped position of pair p
  }
}

// ---------- hidden fp32 -> bf16 ----------
__global__ __launch_bounds__(256) void cvt_hidden_kernel(const float* __restrict__ in,
                                                         unsigned short* __restrict__ outp) {
  const int i = blockIdx.x * 256 + threadIdx.x;
  f32x4 a = ((const f32x4*)in)[(size_t)i * 2];
  f32x4 b = ((const f32x4*)in)[(size_t)i * 2 + 1];
  u16x8 o;
  o[0] = f2bf(a[0]); o[1] = f2bf(a[1]); o[2] = f2bf(a[2]); o[3] = f2bf(a[3]);
  o[4] = f2bf(b[0]); o[5] = f2bf(b[1]); o[6] = f2bf(b[2]); o[7] = f2bf(b[3]);
  ((u16x8*)outp)[i] = o;
}

// ---------- transpose + convert: fp32 [R][C] -> bf16 [C][R] per expert z ----------
__global__ __launch_bounds__(256) void transpose_cvt_kernel(const float* __restrict__ in,
                                                            unsigned short* __restrict__ outp,
                                                            int R, int C) {
  __shared__ float tile[32][33];
  const size_t base = (size_t)blockIdx.z * (size_t)R * (size_t)C;
  const float* ip = in + base;
  unsigned short* op = outp + base;
  const int r0 = blockIdx.y * 32, c0 = blockIdx.x * 32;
  const int i = threadIdx.x >> 3;
  const int j4 = (threadIdx.x & 7) << 2;
  f32x4 v = *(const f32x4*)(ip + (size_t)(r0 + i) * C + c0 + j4);
  tile[i][j4 + 0] = v[0]; tile[i][j4 + 1] = v[1]; tile[i][j4 + 2] = v[2]; tile[i][j4 + 3] = v[3];
  __syncthreads();
  u16x4 o;
  o[0] = f2bf(tile[j4 + 0][i]); o[1] = f2bf(tile[j4 + 1][i]);
  o[2] = f2bf(tile[j4 + 2][i]); o[3] = f2bf(tile[j4 + 3][i]);
  *(u16x4*)(op + (size_t)(c0 + i) * R + r0 + j4) = o;
}

// ---------- grouped GEMM 1: 256x256, 8 waves, BK=32, depth-3 single-barrier ring ----------
// h1 = gelu(hB[tok] @ w1T[e]^T + b1[e]); grid (MB2MAX, 16), 512 threads
__global__ __launch_bounds__(512, 2) void gemm1_kernel(const unsigned short* __restrict__ hB,   // [T][D]
                                                       const unsigned short* __restrict__ w1T,  // [E][F][D]
                                                       const float* __restrict__ b1,            // [E][F]
                                                       const int* __restrict__ g_cnt,
                                                       const int* __restrict__ g_off,
                                                       const int* __restrict__ pairTok,
                                                       const int* __restrict__ blkE2,
                                                       const int* __restrict__ blkM2,
                                                       const int* __restrict__ nMB2,
                                                       unsigned short* __restrict__ h1) {       // [P][F]
  const int flat = blockIdx.x + MB2MAX * blockIdx.y;          // 0..639, 640%8==0
  const int w = (flat & 7) * (MB2MAX * 16 / 8) + (flat >> 3); // chunked XCD swizzle
  const int mI = w % MB2MAX;
  const int nB = w / MB2MAX;
  if (mI >= nMB2[0]) return;
  const int e = blkE2[mI];
  const int m0 = blkM2[mI];
  const int cnt_e = g_cnt[e];
  const int off_e = g_off[e];
  const int rows_e = min(256, cnt_e - m0);
  const int n0 = nB << 8;

  // 4-slot ring: 4 x (256x32 bf16) per operand = 128 KiB
  __shared__ __align__(16) unsigned short As[4][256 * 32];
  __shared__ __align__(16) unsigned short Bs[4][256 * 32];

  const int tid = threadIdx.x;
  const int lane = tid & 63;
  const int wm = (tid >> 6) >> 2;    // 0..1  (M half: 128 rows)
  const int wn = (tid >> 6) & 3;     // 0..3  (N quarter: 64 cols)

  // staging: 2 A + 2 B loads per thread per K-tile; conflict-free swizzle (measured 0 in r5)
  const unsigned short* gA[2];
  const unsigned short* gB[2];
  int ldsP[2];
#pragma unroll
  for (int c = 0; c < 2; ++c) {
    const int p = (c * 512 + tid) * 16;
    const int row = p >> 6;
    const int gu = (tid & 3) ^ ((row >> 1) & 3);
    ldsP[c] = p;
    const int tok = pairTok[off_e + m0 + min(row, rows_e - 1)];
    gA[c] = hB + (size_t)tok * DDIM + (gu << 3);
    gB[c] = w1T + ((size_t)e * FDIM + (n0 + row)) * DDIM + (gu << 3);
  }

  const int kh = lane >> 4;
  const int l15 = lane & 15;
  int aoff[8], boff[4];
#pragma unroll
  for (int i = 0; i < 8; ++i) {
    const int ar = wm * 128 + i * 16 + l15;
    aoff[i] = ar * 64 + ((kh ^ ((ar >> 1) & 3)) << 4);
  }
#pragma unroll
  for (int i = 0; i < 4; ++i) {
    const int br = wn * 64 + i * 16 + l15;
    boff[i] = br * 64 + ((kh ^ ((br >> 1) & 3)) << 4);
  }

  f32x4 acc[8][4];
#pragma unroll
  for (int i = 0; i < 8; ++i)
#pragma unroll
    for (int j = 0; j < 4; ++j) acc[i][j] = (f32x4){0.f, 0.f, 0.f, 0.f};

  // prologue: stage K-tiles 0..2 (12 loads/thread in flight)
#pragma unroll
  for (int p = 0; p < 3; ++p)
#pragma unroll
    for (int c = 0; c < 2; ++c) {
      gload16(gA[c] + (size_t)p * 32, (char*)As[p] + ldsP[c]);
      gload16(gB[c] + (size_t)p * 32, (char*)Bs[p] + ldsP[c]);
    }

  const int KT = DDIM / 32;   // 32
  for (int kt = 0; kt < KT; ++kt) {
    // retire own stage-kt loads (2 newer stages x 4 loads stay in flight)
    if (kt < KT - 2)      { WAITV(8); }
    else if (kt == KT - 2){ WAITV(4); }
    else                  { WAITV(0); }
    BAR();   // all waves: stage-kt visible; all reads of slot (kt+3)&3 (== kt-1) done
    if (kt + 3 < KT) {
      const int sp = (kt + 3) & 3;
#pragma unroll
      for (int c = 0; c < 2; ++c) {
        gload16(gA[c] + (size_t)(kt + 3) * 32, (char*)As[sp] + ldsP[c]);
        gload16(gB[c] + (size_t)(kt + 3) * 32, (char*)Bs[sp] + ldsP[c]);
      }
    }
    const int buf = kt & 3;
    bf16x8 af[8], bv[4];
#pragma unroll
    for (int i = 0; i < 8; ++i) af[i] = *(const bf16x8*)((const char*)As[buf] + aoff[i]);
#pragma unroll
    for (int i = 0; i < 4; ++i) bv[i] = *(const bf16x8*)((const char*)Bs[buf] + boff[i]);
    __builtin_amdgcn_s_setprio(1);
#pragma unroll
    for (int mi = 0; mi < 8; ++mi)
#pragma unroll
      for (int ni = 0; ni < 4; ++ni)
        acc[mi][ni] = __builtin_amdgcn_mfma_f32_16x16x32_bf16(af[mi], bv[ni], acc[mi][ni], 0, 0, 0);
    __builtin_amdgcn_s_setprio(0);
  }

  float bias[4];
#pragma unroll
  for (int ni = 0; ni < 4; ++ni)
    bias[ni] = b1[e * FDIM + n0 + wn * 64 + ni * 16 + l15];
#pragma unroll
  for (int mi = 0; mi < 8; ++mi) {
#pragma unroll
    for (int j = 0; j < 4; ++j) {
      const int row = wm * 128 + mi * 16 + kh * 4 + j;
      if (row < rows_e) {
        unsigned short* dst = h1 + (size_t)(off_e + m0 + row) * FDIM + n0 + wn * 64;
#pragma unroll
        for (int ni = 0; ni < 4; ++ni)
          dst[ni * 16 + l15] = f2bf(gelu_tanh(acc[mi][ni][j] + bias[ni]));
      }
    }
  }
}

// ---------- grouped GEMM 2 (split-K x2): 256x256, 8 waves, BK=32, depth-3 ring ----------
// h2p[s][q] = h1[q] @ w2T[e][:, sK] (+ b2 on s==0); grid (MB2MAX, 4, 2), 512 threads
__global__ __launch_bounds__(512, 2) void gemm2_kernel(const unsigned short* __restrict__ h1,   // [P][F]
                                                       const unsigned short* __restrict__ w2T,  // [E][D][F]
                                                       const float* __restrict__ b2,            // [E][D]
                                                       const int* __restrict__ g_cnt,
                                                       const int* __restrict__ g_off,
                                                       const int* __restrict__ blkE2,
                                                       const int* __restrict__ blkM2,
                                                       const int* __restrict__ nMB2,
                                                       float* __restrict__ h2p) {               // [2][P][D]
  const int flat = blockIdx.x + MB2MAX * blockIdx.y;          // 0..159, 160%8==0
  const int w = (flat & 7) * (MB2MAX * 4 / 8) + (flat >> 3);  // chunked XCD swizzle
  const int mI = w % MB2MAX;
  const int nB = w / MB2MAX;
  if (mI >= nMB2[0]) return;
  const int s = blockIdx.z;
  const int e = blkE2[mI];
  const int m0 = blkM2[mI];
  const int cnt_e = g_cnt[e];
  const int off_e = g_off[e];
  const int rows_e = min(256, cnt_e - m0);
  const int n0 = nB << 8;
  const int kbase = s * (FDIM / 2);

  __shared__ __align__(16) unsigned short As[4][256 * 32];
  __shared__ __align__(16) unsigned short Bs[4][256 * 32];

  const int tid = threadIdx.x;
  const int lane = tid & 63;
  const int wm = (tid >> 6) >> 2;    // 0..1
  const int wn = (tid >> 6) & 3;     // 0..3

  const unsigned short* gA[2];
  const unsigned short* gB[2];
  int ldsP[2];
#pragma unroll
  for (int c = 0; c < 2; ++c) {
    const int p = (c * 512 + tid) * 16;
    const int row = p >> 6;
    const int gu = (tid & 3) ^ ((row >> 1) & 3);
    ldsP[c] = p;
    const int q = off_e + m0 + min(row, rows_e - 1);
    gA[c] = h1 + (size_t)q * FDIM + kbase + (gu << 3);
    gB[c] = w2T + ((size_t)e * DDIM + (n0 + row)) * FDIM + kbase + (gu << 3);
  }

  const int kh = lane >> 4;
  const int l15 = lane & 15;
  int aoff[8], boff[4];
#pragma unroll
  for (int i = 0; i < 8; ++i) {
    const int ar = wm * 128 + i * 16 + l15;
    aoff[i] = ar * 64 + ((kh ^ ((ar >> 1) & 3)) << 4);
  }
#pragma unroll
  for (int i = 0; i < 4; ++i) {
    const int br = wn * 64 + i * 16 + l15;
    boff[i] = br * 64 + ((kh ^ ((br >> 1) & 3)) << 4);
  }

  f32x4 acc[8][4];
#pragma unroll
  for (int i = 0; i < 8; ++i)
#pragma unroll
    for (int j = 0; j < 4; ++j) acc[i][j] = (f32x4){0.f, 0.f, 0.f, 0.f};

#pragma unroll
  for (int p = 0; p < 3; ++p)
#pragma unroll
    for (int c = 0; c < 2; ++c) {
      gload16(gA[c] + (size_t)p * 32, (char*)As[p] + ldsP[c]);
      gload16(gB[c] + (size_t)p * 32, (char*)Bs[p] + ldsP[c]);
    }

  const int KT = (FDIM / 2) / 32;   // 64
  for (int kt = 0; kt < KT; ++kt) {
    if (kt < KT - 2)      { WAITV(8); }
    else if (kt == KT - 2){ WAITV(4); }
    else                  { WAITV(0); }
    BAR();
    if (kt + 3 < KT) {
      const int sp = (kt + 3) & 3;
#pragma unroll
      for (int c = 0; c < 2; ++c) {
        gload16(gA[c] + (size_t)(kt + 3) * 32, (char*)As[sp] + ldsP[c]);
        gload16(gB[c] + (size_t)(kt + 3) * 32, (char*)Bs[sp] + ldsP[c]);
      }
    }
    const int buf = kt & 3;
    bf16x8 af[8], bv[4];
#pragma unroll
    for (int i = 0; i < 8; ++i) af[i] = *(const bf16x8*)((const char*)As[buf] + aoff[i]);
#pragma unroll
    for (int i = 0; i < 4; ++i) bv[i] = *(const bf16x8*)((const char*)Bs[buf] + boff[i]);
    __builtin_amdgcn_s_setprio(1);
#pragma unroll
    for (int mi = 0; mi < 8; ++mi)
#pragma unroll
      for (int ni = 0; ni < 4; ++ni)
        acc[mi][ni] = __builtin_amdgcn_mfma_f32_16x16x32_bf16(af[mi], bv[ni], acc[mi][ni], 0, 0, 0);
    __builtin_amdgcn_s_setprio(0);
  }

  float* outBase = h2p + (size_t)s * PPAIR * DDIM;
#pragma unroll
  for (int mi = 0; mi < 8; ++mi) {
#pragma unroll
    for (int j = 0; j < 4; ++j) {
      const int row = wm * 128 + mi * 16 + kh * 4 + j;
      if (row < rows_e) {
        float* dp = outBase + (size_t)(off_e + m0 + row) * DDIM;
#pragma unroll
        for (int ni = 0; ni < 4; ++ni) {
          const int col = n0 + wn * 64 + ni * 16 + l15;
          float v = acc[mi][ni][j];
          if (s == 0) v += b2[e * DDIM + col];
          dp[col] = v;
        }
      }
    }
  }
}

// ---------- combine ----------
__global__ __launch_bounds__(256) void combine_kernel(const float* __restrict__ h2p,
                                                      const float* __restrict__ ew,
                                                      const int* __restrict__ inv,
                                                      float* __restrict__ out) {
  const int i = blockIdx.x * 256 + threadIdx.x;  // over TTOK*DDIM/4
  const int t = i >> 8;
  const int c = i & 255;
  const int q0 = inv[t * 2], q1 = inv[t * 2 + 1];
  const float wa = ew[t * 2], wb = ew[t * 2 + 1];
  const f32x4* p0 = (const f32x4*)h2p;
  const f32x4* p1 = (const f32x4*)(h2p + (size_t)PPAIR * DDIM);
  f32x4 r = (p0[(size_t)q0 * 256 + c] + p1[(size_t)q0 * 256 + c]) * wa
          + (p0[(size_t)q1 * 256 + c] + p1[(size_t)q1 * 256 + c]) * wb;
  ((f32x4*)out)[i] = r;
}

// ---------- launch ----------
extern "C" void kernel_launch(void* const* d_in, const int* in_sizes, int n_in,
                              void* d_out, int out_size, void* d_ws, size_t ws_size,
                              hipStream_t stream) {
  (void)in_sizes; (void)n_in; (void)out_size; (void)ws_size;
  const float* hidden = (const float*)d_in[0];
  const int*   eidx   = (const int*)d_in[1];
  const float* ew     = (const float*)d_in[2];
  const float* rlog   = (const float*)d_in[3];
  const float* w1     = (const float*)d_in[4];
  const float* b1     = (const float*)d_in[5];
  const float* w2     = (const float*)d_in[6];
  const float* b2     = (const float*)d_in[7];
  float* out = (float*)d_out;

  char* wsb = (char*)d_ws;
  const size_t SZ_W = (size_t)ENUM * DDIM * FDIM * 2;  // 64 MiB (bf16)
  unsigned short* w1T = (unsigned short*)(wsb);
  unsigned short* w2T = (unsigned short*)(wsb + SZ_W);
  unsigned short* hB  = (unsigned short*)(wsb + 2 * SZ_W);
  unsigned short* h1  = (unsigned short*)(wsb + 2 * SZ_W + (size_t)TTOK * DDIM * 2);
  int* g_cnt   = (int*)(wsb + 2 * SZ_W + (size_t)TTOK * DDIM * 2 + (size_t)PPAIR * FDIM * 2);
  int* g_off   = g_cnt + 8;
  int* pairTok = g_off + 8;
  int* inv     = pairTok + PPAIR;
  int* blkE2   = inv + PPAIR;
  int* blkM2   = blkE2 + MB2MAX;
  int* nMB2    = blkM2 + MB2MAX;
  float* pstats = (float*)(nMB2 + 1);
  // h2p (2 x 8192 x 1024 fp32 = 64 MiB) aliases w1T exactly (dead after gemm1)
  float* h2p = (float*)wsb;

  statsA_kernel<<<16, 256, 0, stream>>>(rlog, pstats);
  statsB_kernel<<<1, 64, 0, stream>>>(pstats, out);
  routing_kernel<<<1, 256, 0, stream>>>(eidx, g_cnt, g_off, pairTok, inv, blkE2, blkM2, nMB2);
  cvt_hidden_kernel<<<(TTOK * DDIM / 8 + 255) / 256, 256, 0, stream>>>(hidden, hB);
  transpose_cvt_kernel<<<dim3(FDIM / 32, DDIM / 32, ENUM), 256, 0, stream>>>(w1, w1T, DDIM, FDIM);
  transpose_cvt_kernel<<<dim3(DDIM / 32, FDIM / 32, ENUM), 256, 0, stream>>>(w2, w2T, FDIM, DDIM);
  gemm1_kernel<<<dim3(MB2MAX, FDIM / 256), 512, 0, stream>>>(hB, w1T, b1, g_cnt, g_off, pairTok, blkE2, blkM2, nMB2, h1);
  gemm2_kernel<<<dim3(MB2MAX, DDIM / 256, 2), 512, 0, stream>>>(h1, w2T, b2, g_cnt, g_off, blkE2, blkM2, nMB2, h2p);
  combine_kernel<<<(TTOK * DDIM / 4) / 256, 256, 0, stream>>>(h2p, ew, inv, out);
}

// Round 7
// 397.850 us; speedup vs baseline: 1.0856x; 1.0856x over previous
//
#include <hip/hip_runtime.h>
#include <stddef.h>
#include <stdint.h>

// ---------- problem dims (fixed by setup_inputs) ----------
#define BDIM 2
#define SDIM 2048
#define DDIM 1024
#define FDIM 4096
#define ENUM 8
#define KSEL 2
#define TTOK (BDIM * SDIM)        // 4096 tokens
#define PPAIR (TTOK * KSEL)       // 8192 (token,k) pairs
#define VOUT ((size_t)TTOK * DDIM) // 4194304 floats of "mixed"
#define MB2MAX 40                 // 256-granular m-blocks: sum ceil(cnt_e/256) <= 32+8

typedef float f32x4 __attribute__((ext_vector_type(4)));
typedef short bf16x8 __attribute__((ext_vector_type(8)));
typedef unsigned short u16x8 __attribute__((ext_vector_type(8)));
typedef unsigned short u16x4 __attribute__((ext_vector_type(4)));

#define WAITV(N) asm volatile("s_waitcnt vmcnt(" #N ")" ::: "memory")
#define BAR() __builtin_amdgcn_s_barrier()

__device__ __forceinline__ unsigned short f2bf(float f) {
  unsigned int u = __float_as_uint(f);
  u += 0x7fffu + ((u >> 16) & 1u);   // RNE
  return (unsigned short)(u >> 16);
}

__device__ __forceinline__ float gelu_tanh(float x) {
  float u = 0.7978845608028654f * (x + 0.044715f * x * x * x);
  float e = __expf(2.0f * u);
  float t = 1.0f - 2.0f / (e + 1.0f);   // tanh(u), safe at +-inf
  return 0.5f * x * (1.0f + t);
}

__device__ __forceinline__ void gload16(const void* g, void* l) {
  __builtin_amdgcn_global_load_lds(
      (const __attribute__((address_space(1))) unsigned int*)g,
      (__attribute__((address_space(3))) unsigned int*)l, 16, 0, 0);
}

// ---------- router stats, stage A ----------
__global__ __launch_bounds__(256) void statsA_kernel(const float* __restrict__ lg,
                                                     float* __restrict__ pst) {
  __shared__ float se[256], sm[256];
  const int r = blockIdx.x * 256 + threadIdx.x;
  float v[ENUM];
  float mx = -1e30f;
#pragma unroll
  for (int i = 0; i < ENUM; ++i) { v[i] = lg[r * ENUM + i]; mx = fmaxf(mx, v[i]); }
  float s = 0.f;
#pragma unroll
  for (int i = 0; i < ENUM; ++i) { v[i] = __expf(v[i] - mx); s += v[i]; }
  float inv = 1.f / s;
  float p1 = -1.f, p2 = -1.f, e_ = 0.f;
#pragma unroll
  for (int i = 0; i < ENUM; ++i) {
    float p = v[i] * inv;
    e_ -= p * logf(fmaxf(p, 1e-9f));
    if (p > p1) { p2 = p1; p1 = p; } else if (p > p2) { p2 = p; }
  }
  se[threadIdx.x] = e_; sm[threadIdx.x] = p1 - p2;
  __syncthreads();
  for (int st = 128; st > 0; st >>= 1) {
    if (threadIdx.x < (unsigned)st) { se[threadIdx.x] += se[threadIdx.x + st]; sm[threadIdx.x] += sm[threadIdx.x + st]; }
    __syncthreads();
  }
  if (threadIdx.x == 0) { pst[blockIdx.x * 2] = se[0]; pst[blockIdx.x * 2 + 1] = sm[0]; }
}

// ---------- router stats, stage B ----------
__global__ void statsB_kernel(const float* __restrict__ pst, float* __restrict__ out) {
  if (threadIdx.x == 0) {
    float a = 0.f, b = 0.f;
    for (int i = 0; i < 16; ++i) { a += pst[2 * i]; b += pst[2 * i + 1]; }
    out[VOUT]     = a / (float)TTOK;
    out[VOUT + 1] = b / (float)TTOK;
  }
}

// ---------- routing: group pairs by expert; 256-granular block table ----------
__global__ __launch_bounds__(256) void routing_kernel(const int* __restrict__ eidx,
                                                      int* __restrict__ g_cnt,
                                                      int* __restrict__ g_off,
                                                      int* __restrict__ pairTok,
                                                      int* __restrict__ inv,
                                                      int* __restrict__ blkE2,
                                                      int* __restrict__ blkM2,
                                                      int* __restrict__ nMB2) {
  __shared__ int sc[ENUM], so[ENUM], scur[ENUM];
  const int tid = threadIdx.x;
  if (tid < ENUM) sc[tid] = 0;
  __syncthreads();
  for (int p = tid; p < PPAIR; p += 256) atomicAdd(&sc[eidx[p]], 1);
  __syncthreads();
  if (tid == 0) {
    int o = 0, nb2 = 0;
    for (int e = 0; e < ENUM; ++e) {
      so[e] = o;
      for (int m0 = 0; m0 < sc[e]; m0 += 256) { blkE2[nb2] = e; blkM2[nb2] = m0; ++nb2; }
      o += sc[e];
    }
    nMB2[0] = nb2;
  }
  __syncthreads();
  if (tid < ENUM) { scur[tid] = so[tid]; g_cnt[tid] = sc[tid]; g_off[tid] = so[tid]; }
  __syncthreads();
  for (int p = tid; p < PPAIR; p += 256) {
    int e = eidx[p];
    int pos = atomicAdd(&scur[e], 1);
    pairTok[pos] = p >> 1;  // token id
    inv[p] = pos;           // grouped position of pair p
  }
}

// ---------- hidden fp32 -> bf16 ----------
__global__ __launch_bounds__(256) void cvt_hidden_kernel(const float* __restrict__ in,
                                                         unsigned short* __restrict__ outp) {
  const int i = blockIdx.x * 256 + threadIdx.x;
  f32x4 a = ((const f32x4*)in)[(size_t)i * 2];
  f32x4 b = ((const f32x4*)in)[(size_t)i * 2 + 1];
  u16x8 o;
  o[0] = f2bf(a[0]); o[1] = f2bf(a[1]); o[2] = f2bf(a[2]); o[3] = f2bf(a[3]);
  o[4] = f2bf(b[0]); o[5] = f2bf(b[1]); o[6] = f2bf(b[2]); o[7] = f2bf(b[3]);
  ((u16x8*)outp)[i] = o;
}

// ---------- transpose + convert: fp32 [R][C] -> bf16 [C][R] per expert z ----------
__global__ __launch_bounds__(256) void transpose_cvt_kernel(const float* __restrict__ in,
                                                            unsigned short* __restrict__ outp,
                                                            int R, int C) {
  __shared__ float tile[32][33];
  const size_t base = (size_t)blockIdx.z * (size_t)R * (size_t)C;
  const float* ip = in + base;
  unsigned short* op = outp + base;
  const int r0 = blockIdx.y * 32, c0 = blockIdx.x * 32;
  const int i = threadIdx.x >> 3;
  const int j4 = (threadIdx.x & 7) << 2;
  f32x4 v = *(const f32x4*)(ip + (size_t)(r0 + i) * C + c0 + j4);
  tile[i][j4 + 0] = v[0]; tile[i][j4 + 1] = v[1]; tile[i][j4 + 2] = v[2]; tile[i][j4 + 3] = v[3];
  __syncthreads();
  u16x4 o;
  o[0] = f2bf(tile[j4 + 0][i]); o[1] = f2bf(tile[j4 + 1][i]);
  o[2] = f2bf(tile[j4 + 2][i]); o[3] = f2bf(tile[j4 + 3][i]);
  *(u16x4*)(op + (size_t)(c0 + i) * R + r0 + j4) = o;
}

// ---------- grouped GEMM 1: 256x256, 8 waves, BK=64, dbuf, 2-phase (m230-V0 structure) ----------
// h1 = gelu(hB[tok] @ w1T[e]^T + b1[e]); grid (MB2MAX, 16), 512 threads
__global__ __launch_bounds__(512, 2) void gemm1_kernel(const unsigned short* __restrict__ hB,   // [T][D]
                                                       const unsigned short* __restrict__ w1T,  // [E][F][D]
                                                       const float* __restrict__ b1,            // [E][F]
                                                       const int* __restrict__ g_cnt,
                                                       const int* __restrict__ g_off,
                                                       const int* __restrict__ pairTok,
                                                       const int* __restrict__ blkE2,
                                                       const int* __restrict__ blkM2,
                                                       const int* __restrict__ nMB2,
                                                       unsigned short* __restrict__ h1) {       // [P][F]
  const int flat = blockIdx.x + MB2MAX * blockIdx.y;          // 0..639, 640%8==0
  const int w = (flat & 7) * (MB2MAX * 16 / 8) + (flat >> 3); // chunked XCD swizzle
  const int mI = w % MB2MAX;
  const int nB = w / MB2MAX;
  if (mI >= nMB2[0]) return;
  const int e = blkE2[mI];
  const int m0 = blkM2[mI];
  const int cnt_e = g_cnt[e];
  const int off_e = g_off[e];
  const int rows_e = min(256, cnt_e - m0);
  const int n0 = nB << 8;

  // double buffer: 2 x [256][64] bf16 per operand = 128 KiB
  __shared__ __align__(16) unsigned short As[2][256 * 64];
  __shared__ __align__(16) unsigned short Bs[2][256 * 64];

  const int tid = threadIdx.x;
  const int lane = tid & 63;
  const int wm = (tid >> 6) >> 2;    // 0..1  (M half: 128 rows)
  const int wn = (tid >> 6) & 3;     // 0..3  (N quarter: 64 cols)

  // staging: 4 A + 4 B loads per thread per K-tile (BK=64; rows are 128 B = 8 granules of 16 B)
  // LDS byte p: row = p>>7, slot-granule sg=(p>>4)&7; content granule g = sg ^ (row&7)
  const unsigned short* gA[4];
  const unsigned short* gB[4];
  int ldsP[4];
#pragma unroll
  for (int c = 0; c < 4; ++c) {
    const int p = (c * 512 + tid) * 16;
    const int row = p >> 7;
    const int g = ((p >> 4) & 7) ^ (row & 7);
    ldsP[c] = p;
    const int tok = pairTok[off_e + m0 + min(row, rows_e - 1)];
    gA[c] = hB + (size_t)tok * DDIM + (g << 3);
    gB[c] = w1T + ((size_t)e * FDIM + (n0 + row)) * DDIM + (g << 3);
  }

  // read offsets (bytes): frag row r, K-slice ks, k-quarter kh: stored granule = ((ks<<2)|kh) ^ (r&7)
  const int kh = lane >> 4;          // 0..3
  const int l15 = lane & 15;
  int aoff[8][2], boff[4][2];
#pragma unroll
  for (int i = 0; i < 8; ++i) {
    const int ar = wm * 128 + i * 16 + l15;
#pragma unroll
    for (int ks = 0; ks < 2; ++ks)
      aoff[i][ks] = ar * 128 + ((((ks << 2) | kh) ^ (ar & 7)) << 4);
  }
#pragma unroll
  for (int i = 0; i < 4; ++i) {
    const int br = wn * 64 + i * 16 + l15;
#pragma unroll
    for (int ks = 0; ks < 2; ++ks)
      boff[i][ks] = br * 128 + ((((ks << 2) | kh) ^ (br & 7)) << 4);
  }

  f32x4 acc[8][4];
#pragma unroll
  for (int i = 0; i < 8; ++i)
#pragma unroll
    for (int j = 0; j < 4; ++j) acc[i][j] = (f32x4){0.f, 0.f, 0.f, 0.f};

  // prologue: stage tile 0
#pragma unroll
  for (int c = 0; c < 4; ++c) {
    gload16(gA[c], (char*)As[0] + ldsP[c]);
    gload16(gB[c], (char*)Bs[0] + ldsP[c]);
  }
  WAITV(0);
  BAR();

  int cur = 0;
  const int KT = DDIM / 64;   // 16
  for (int kt = 0; kt < KT; ++kt) {
    if (kt + 1 < KT) {
#pragma unroll
      for (int c = 0; c < 4; ++c) {
        gload16(gA[c] + (size_t)(kt + 1) * 64, (char*)As[cur ^ 1] + ldsP[c]);
        gload16(gB[c] + (size_t)(kt + 1) * 64, (char*)Bs[cur ^ 1] + ldsP[c]);
      }
    }
#pragma unroll
    for (int ks = 0; ks < 2; ++ks) {
      bf16x8 af[8], bv[4];
#pragma unroll
      for (int i = 0; i < 8; ++i) af[i] = *(const bf16x8*)((const char*)As[cur] + aoff[i][ks]);
#pragma unroll
      for (int i = 0; i < 4; ++i) bv[i] = *(const bf16x8*)((const char*)Bs[cur] + boff[i][ks]);
      __builtin_amdgcn_s_setprio(1);
#pragma unroll
      for (int mi = 0; mi < 8; ++mi)
#pragma unroll
        for (int ni = 0; ni < 4; ++ni)
          acc[mi][ni] = __builtin_amdgcn_mfma_f32_16x16x32_bf16(af[mi], bv[ni], acc[mi][ni], 0, 0, 0);
      __builtin_amdgcn_s_setprio(0);
    }
    WAITV(0);   // staged tile kt+1 landed (drain hidden behind the 64 MFMAs above)
    BAR();
    cur ^= 1;
  }

  float bias[4];
#pragma unroll
  for (int ni = 0; ni < 4; ++ni)
    bias[ni] = b1[e * FDIM + n0 + wn * 64 + ni * 16 + l15];
#pragma unroll
  for (int mi = 0; mi < 8; ++mi) {
#pragma unroll
    for (int j = 0; j < 4; ++j) {
      const int row = wm * 128 + mi * 16 + kh * 4 + j;
      if (row < rows_e) {
        unsigned short* dst = h1 + (size_t)(off_e + m0 + row) * FDIM + n0 + wn * 64;
#pragma unroll
        for (int ni = 0; ni < 4; ++ni)
          dst[ni * 16 + l15] = f2bf(gelu_tanh(acc[mi][ni][j] + bias[ni]));
      }
    }
  }
}

// ---------- grouped GEMM 2 (split-K x2): 256x256, 8 waves, BK=64, dbuf, 2-phase ----------
// h2p[s][q] = h1[q] @ w2T[e][:, sK] (+ b2 on s==0); grid (MB2MAX, 4, 2), 512 threads
__global__ __launch_bounds__(512, 2) void gemm2_kernel(const unsigned short* __restrict__ h1,   // [P][F]
                                                       const unsigned short* __restrict__ w2T,  // [E][D][F]
                                                       const float* __restrict__ b2,            // [E][D]
                                                       const int* __restrict__ g_cnt,
                                                       const int* __restrict__ g_off,
                                                       const int* __restrict__ blkE2,
                                                       const int* __restrict__ blkM2,
                                                       const int* __restrict__ nMB2,
                                                       float* __restrict__ h2p) {               // [2][P][D]
  const int flat = blockIdx.x + MB2MAX * blockIdx.y;          // 0..159, 160%8==0
  const int w = (flat & 7) * (MB2MAX * 4 / 8) + (flat >> 3);  // chunked XCD swizzle
  const int mI = w % MB2MAX;
  const int nB = w / MB2MAX;
  if (mI >= nMB2[0]) return;
  const int s = blockIdx.z;
  const int e = blkE2[mI];
  const int m0 = blkM2[mI];
  const int cnt_e = g_cnt[e];
  const int off_e = g_off[e];
  const int rows_e = min(256, cnt_e - m0);
  const int n0 = nB << 8;
  const int kbase = s * (FDIM / 2);

  __shared__ __align__(16) unsigned short As[2][256 * 64];
  __shared__ __align__(16) unsigned short Bs[2][256 * 64];

  const int tid = threadIdx.x;
  const int lane = tid & 63;
  const int wm = (tid >> 6) >> 2;    // 0..1
  const int wn = (tid >> 6) & 3;     // 0..3

  const unsigned short* gA[4];
  const unsigned short* gB[4];
  int ldsP[4];
#pragma unroll
  for (int c = 0; c < 4; ++c) {
    const int p = (c * 512 + tid) * 16;
    const int row = p >> 7;
    const int g = ((p >> 4) & 7) ^ (row & 7);
    ldsP[c] = p;
    const int q = off_e + m0 + min(row, rows_e - 1);
    gA[c] = h1 + (size_t)q * FDIM + kbase + (g << 3);
    gB[c] = w2T + ((size_t)e * DDIM + (n0 + row)) * FDIM + kbase + (g << 3);
  }

  const int kh = lane >> 4;
  const int l15 = lane & 15;
  int aoff[8][2], boff[4][2];
#pragma unroll
  for (int i = 0; i < 8; ++i) {
    const int ar = wm * 128 + i * 16 + l15;
#pragma unroll
    for (int ks = 0; ks < 2; ++ks)
      aoff[i][ks] = ar * 128 + ((((ks << 2) | kh) ^ (ar & 7)) << 4);
  }
#pragma unroll
  for (int i = 0; i < 4; ++i) {
    const int br = wn * 64 + i * 16 + l15;
#pragma unroll
    for (int ks = 0; ks < 2; ++ks)
      boff[i][ks] = br * 128 + ((((ks << 2) | kh) ^ (br & 7)) << 4);
  }

  f32x4 acc[8][4];
#pragma unroll
  for (int i = 0; i < 8; ++i)
#pragma unroll
    for (int j = 0; j < 4; ++j) acc[i][j] = (f32x4){0.f, 0.f, 0.f, 0.f};

#pragma unroll
  for (int c = 0; c < 4; ++c) {
    gload16(gA[c], (char*)As[0] + ldsP[c]);
    gload16(gB[c], (char*)Bs[0] + ldsP[c]);
  }
  WAITV(0);
  BAR();

  int cur = 0;
  const int KT = (FDIM / 2) / 64;   // 32
  for (int kt = 0; kt < KT; ++kt) {
    if (kt + 1 < KT) {
#pragma unroll
      for (int c = 0; c < 4; ++c) {
        gload16(gA[c] + (size_t)(kt + 1) * 64, (char*)As[cur ^ 1] + ldsP[c]);
        gload16(gB[c] + (size_t)(kt + 1) * 64, (char*)Bs[cur ^ 1] + ldsP[c]);
      }
    }
#pragma unroll
    for (int ks = 0; ks < 2; ++ks) {
      bf16x8 af[8], bv[4];
#pragma unroll
      for (int i = 0; i < 8; ++i) af[i] = *(const bf16x8*)((const char*)As[cur] + aoff[i][ks]);
#pragma unroll
      for (int i = 0; i < 4; ++i) bv[i] = *(const bf16x8*)((const char*)Bs[cur] + boff[i][ks]);
      __builtin_amdgcn_s_setprio(1);
#pragma unroll
      for (int mi = 0; mi < 8; ++mi)
#pragma unroll
        for (int ni = 0; ni < 4; ++ni)
          acc[mi][ni] = __builtin_amdgcn_mfma_f32_16x16x32_bf16(af[mi], bv[ni], acc[mi][ni], 0, 0, 0);
      __builtin_amdgcn_s_setprio(0);
    }
    WAITV(0);
    BAR();
    cur ^= 1;
  }

  float* outBase = h2p + (size_t)s * PPAIR * DDIM;
#pragma unroll
  for (int mi = 0; mi < 8; ++mi) {
#pragma unroll
    for (int j = 0; j < 4; ++j) {
      const int row = wm * 128 + mi * 16 + kh * 4 + j;
      if (row < rows_e) {
        float* dp = outBase + (size_t)(off_e + m0 + row) * DDIM;
#pragma unroll
        for (int ni = 0; ni < 4; ++ni) {
          const int col = n0 + wn * 64 + ni * 16 + l15;
          float v = acc[mi][ni][j];
          if (s == 0) v += b2[e * DDIM + col];
          dp[col] = v;
        }
      }
    }
  }
}

// ---------- combine ----------
__global__ __launch_bounds__(256) void combine_kernel(const float* __restrict__ h2p,
                                                      const float* __restrict__ ew,
                                                      const int* __restrict__ inv,
                                                      float* __restrict__ out) {
  const int i = blockIdx.x * 256 + threadIdx.x;  // over TTOK*DDIM/4
  const int t = i >> 8;
  const int c = i & 255;
  const int q0 = inv[t * 2], q1 = inv[t * 2 + 1];
  const float wa = ew[t * 2], wb = ew[t * 2 + 1];
  const f32x4* p0 = (const f32x4*)h2p;
  const f32x4* p1 = (const f32x4*)(h2p + (size_t)PPAIR * DDIM);
  f32x4 r = (p0[(size_t)q0 * 256 + c] + p1[(size_t)q0 * 256 + c]) * wa
          + (p0[(size_t)q1 * 256 + c] + p1[(size_t)q1 * 256 + c]) * wb;
  ((f32x4*)out)[i] = r;
}

// ---------- launch ----------
extern "C" void kernel_launch(void* const* d_in, const int* in_sizes, int n_in,
                              void* d_out, int out_size, void* d_ws, size_t ws_size,
                              hipStream_t stream) {
  (void)in_sizes; (void)n_in; (void)out_size; (void)ws_size;
  const float* hidden = (const float*)d_in[0];
  const int*   eidx   = (const int*)d_in[1];
  const float* ew     = (const float*)d_in[2];
  const float* rlog   = (const float*)d_in[3];
  const float* w1     = (const float*)d_in[4];
  const float* b1     = (const float*)d_in[5];
  const float* w2     = (const float*)d_in[6];
  const float* b2     = (const float*)d_in[7];
  float* out = (float*)d_out;

  char* wsb = (char*)d_ws;
  const size_t SZ_W = (size_t)ENUM * DDIM * FDIM * 2;  // 64 MiB (bf16)
  unsigned short* w1T = (unsigned short*)(wsb);
  unsigned short* w2T = (unsigned short*)(wsb + SZ_W);
  unsigned short* hB  = (unsigned short*)(wsb + 2 * SZ_W);
  unsigned short* h1  = (unsigned short*)(wsb + 2 * SZ_W + (size_t)TTOK * DDIM * 2);
  int* g_cnt   = (int*)(wsb + 2 * SZ_W + (size_t)TTOK * DDIM * 2 + (size_t)PPAIR * FDIM * 2);
  int* g_off   = g_cnt + 8;
  int* pairTok = g_off + 8;
  int* inv     = pairTok + PPAIR;
  int* blkE2   = inv + PPAIR;
  int* blkM2   = blkE2 + MB2MAX;
  int* nMB2    = blkM2 + MB2MAX;
  float* pstats = (float*)(nMB2 + 1);
  // h2p (2 x 8192 x 1024 fp32 = 64 MiB) aliases w1T exactly (dead after gemm1)
  float* h2p = (float*)wsb;

  statsA_kernel<<<16, 256, 0, stream>>>(rlog, pstats);
  statsB_kernel<<<1, 64, 0, stream>>>(pstats, out);
  routing_kernel<<<1, 256, 0, stream>>>(eidx, g_cnt, g_off, pairTok, inv, blkE2, blkM2, nMB2);
  cvt_hidden_kernel<<<(TTOK * DDIM / 8 + 255) / 256, 256, 0, stream>>>(hidden, hB);
  transpose_cvt_kernel<<<dim3(FDIM / 32, DDIM / 32, ENUM), 256, 0, stream>>>(w1, w1T, DDIM, FDIM);
  transpose_cvt_kernel<<<dim3(DDIM / 32, FDIM / 32, ENUM), 256, 0, stream>>>(w2, w2T, FDIM, DDIM);
  gemm1_kernel<<<dim3(MB2MAX, FDIM / 256), 512, 0, stream>>>(hB, w1T, b1, g_cnt, g_off, pairTok, blkE2, blkM2, nMB2, h1);
  gemm2_kernel<<<dim3(MB2MAX, DDIM / 256, 2), 512, 0, stream>>>(h1, w2T, b2, g_cnt, g_off, blkE2, blkM2, nMB2, h2p);
  combine_kernel<<<(TTOK * DDIM / 4) / 256, 256, 0, stream>>>(h2p, ew, inv, out);
}